// Round 6
// baseline (218.654 us; speedup 1.0000x reference)
//
#include <hip/hip_runtime.h>

// Problem constants
#define BATCH   32
#define CIN     256
#define COUT    64
#define HW      1024          // 32*32
#define NE      1024          // codebook size
#define ED      64            // code dim
#define ZTOT    2097152       // BATCH*COUT*HW

// d_out layout (floats): z_q_st[ZTOT], loss[1], sampled[32768], min_idx[32768]
#define OFF_LOSS 2097152
#define OFF_SAMP 2097153
#define OFF_IDX  2129921

// LDS strides (floats)
#define CSTR 66     // conv Xs/Ws [64 c][64 + 2]
#define ESTR 132    // dist es [64 k][128 code + 4]  == 2*CSTR (exact SH alias)
#define ZSTR 68     // dist zs [64 k(px)][64 row(o) + 4]

// ---------------------------------------------------------------------------
// k_con: prep. blocks 0..127 zero sampled (+counter); 128..143 contrast
// partials (block-local inv-norms, bit-identical); 144..147 enorm.
__global__ __launch_bounds__(256) void k_con(const float* __restrict__ emb,
                                             float* __restrict__ out_samp,
                                             float* __restrict__ enorm,
                                             float* __restrict__ cpart,
                                             unsigned int* __restrict__ counter) {
    __shared__ float SHc[320];
    int bx = blockIdx.x;
    int t  = threadIdx.x;
    if (bx < 128) {                       // ---- zero sampled
        if (bx == 0 && t == 0) *counter = 0u;
        out_samp[bx * 256 + t] = 0.0f;
        return;
    }
    if (bx < 144) {                       // ---- contrast partial (16 blocks)
        float* invl = SHc;                // [64]
        float* S    = SHc + 64;           // [256]
        int b2 = bx - 128;
        int i0 = b2 * 64;
        if (t < 64) {
            const float* e = emb + (size_t)(i0 + t) * ED;
            float r8[8];
            #pragma unroll
            for (int s = 0; s < 8; s++) { float xx = e[s]; r8[s] = xx * xx; }
            #pragma unroll
            for (int m = 1; m < 8; m++) {
                #pragma unroll
                for (int s = 0; s < 8; s++) { float xx = e[8 * m + s]; r8[s] += xx * xx; }
            }
            float en = ((r8[0] + r8[1]) + (r8[2] + r8[3])) + ((r8[4] + r8[5]) + (r8[6] + r8[7]));
            invl[t] = 1.0f / sqrtf(en);
        }
        __syncthreads();
        int d = t & 63, q = t >> 6;
        float s = 0.0f;
        #pragma unroll
        for (int m = 0; m < 16; m++) {
            int il = q + 4 * m;
            s = fmaf(emb[(size_t)(i0 + il) * ED + d], invl[il], s);
        }
        S[t] = s;
        __syncthreads();
        if (t < 64)
            cpart[b2 * 64 + t] = (S[t] + S[t + 64]) + (S[t + 128] + S[t + 192]);
        return;
    }
    {                                     // ---- enorm (4 blocks)
        int j = (bx - 144) * 256 + t;     // 0..1023
        const float* e = emb + (size_t)j * ED;
        float r8[8];
        #pragma unroll
        for (int s = 0; s < 8; s++) { float xx = e[s]; r8[s] = xx * xx; }
        #pragma unroll
        for (int m = 1; m < 8; m++) {
            #pragma unroll
            for (int s = 0; s < 8; s++) { float xx = e[8 * m + s]; r8[s] += xx * xx; }
        }
        enorm[j] = ((r8[0] + r8[1]) + (r8[2] + r8[3])) + ((r8[4] + r8[5]) + (r8[6] + r8[7]));
    }
}

// ---------------------------------------------------------------------------
// k_fused: conv + distance/argmin + STE + loss, one kernel, 512 blocks.
// Block (b, p16): batch b, pixel tile p0=64*p16. Flattening identity:
//   zf row n = b*1024 + o*16 + p16,  element e = p - p0   (o = 0..63)
// so this block's conv output IS 64 complete zf rows. Conv epilogue writes
// bias-added accumulators straight into zs[k=e][r=o] (transposed, LDS) --
// wz global round-trip eliminated. Dist phase is v0's proven loop verbatim
// (4 rows x 8 codes, 128-code full-K chunks, k-major, conflict-free).
// All value-producing chains (conv c-seq fmaf, pairwise norms, k-asc dot,
// strict-< first-min argmin, STE forms) byte-identical to passing versions.
__global__ __launch_bounds__(256, 2) void k_fused(const float* __restrict__ x,
                                                  const float* __restrict__ w,
                                                  const float* __restrict__ bias,
                                                  const float* __restrict__ emb,
                                                  const float* __restrict__ enorm,
                                                  const float* __restrict__ cpart,
                                                  float* __restrict__ out_idx,
                                                  float* __restrict__ out_samp,
                                                  float* __restrict__ out_zq,
                                                  float* __restrict__ ssep,
                                                  float* __restrict__ out_loss,
                                                  unsigned int* __restrict__ counter) {
    __shared__ float SH[64 * CSTR * 2];   // 8448 floats = 33.8 KB: Xs/Ws, then es/scratch
    __shared__ float zs[64 * ZSTR];       // 17.4 KB  [k=e][r=o]
    __shared__ float zn_s[64];
    __shared__ float en_s[128];
    __shared__ float warr[4];
    __shared__ int   bj_s[64];
    __shared__ int   lastflag;
    __shared__ float CS;
    __shared__ double SD[256];            // final-block loss tree
    float* redd_s = SH;                   // [16][64] overlay after es dead
    int*   redj_s = (int*)(SH + 1024);    // [16][64]

    int t  = threadIdx.x;
    int bx = blockIdx.x;
    int b   = bx >> 4;                    // 0..31
    int p16 = bx & 15;                    // 0..15
    int p0  = p16 * 64;

    // ---------------- conv phase (R1-proven tiling, values bit-identical) ----
    {
        float* Xs = SH;                   // [64 c][CSTR]
        float* Ws = SH + 64 * CSTR;       // [64 c][CSTR]
        int pg = t & 15;                  // px: 4*pg + i
        int og = t >> 4;                  // o : 4*og + j
        float acc[4][4];
        #pragma unroll
        for (int i = 0; i < 4; i++)
            #pragma unroll
            for (int j = 0; j < 4; j++) acc[i][j] = 0.0f;

        for (int c0 = 0; c0 < CIN; c0 += 64) {
            __syncthreads();
            {
                int u = t & 15, cg2 = t >> 4;
                #pragma unroll
                for (int m = 0; m < 4; m++) {
                    int c = cg2 + 16 * m;
                    float4 v = *(const float4*)&x[(size_t)(b * CIN + c0 + c) * HW + p0 + 4 * u];
                    *(float4*)&Xs[c * CSTR + 4 * u] = v;
                }
                #pragma unroll
                for (int m = 0; m < 4; m++) {
                    int o = cg2 + 16 * m;
                    float4 v = *(const float4*)&w[o * CIN + c0 + 4 * u];
                    Ws[(4 * u + 0) * CSTR + o] = v.x;
                    Ws[(4 * u + 1) * CSTR + o] = v.y;
                    Ws[(4 * u + 2) * CSTR + o] = v.z;
                    Ws[(4 * u + 3) * CSTR + o] = v.w;
                }
            }
            __syncthreads();
            #pragma unroll 8
            for (int k = 0; k < 64; k++) {
                float4 xv = *(const float4*)&Xs[k * CSTR + 4 * pg];
                float4 wv = *(const float4*)&Ws[k * CSTR + 4 * og];
                float xa[4] = {xv.x, xv.y, xv.z, xv.w};
                float wb[4] = {wv.x, wv.y, wv.z, wv.w};
                #pragma unroll
                for (int i = 0; i < 4; i++)
                    #pragma unroll
                    for (int j = 0; j < 4; j++)
                        acc[i][j] = fmaf(xa[i], wb[j], acc[i][j]);
            }
        }
        // epilogue: add bias, write transposed into zs[k=px_local][r=o]
        float4 bv4 = *(const float4*)&bias[4 * og];
        #pragma unroll
        for (int i = 0; i < 4; i++) {
            float4 w4;
            w4.x = acc[i][0] + bv4.x;
            w4.y = acc[i][1] + bv4.y;
            w4.z = acc[i][2] + bv4.z;
            w4.w = acc[i][3] + bv4.w;
            *(float4*)&zs[(4 * pg + i) * ZSTR + 4 * og] = w4;
        }
    }
    __syncthreads();                      // zs complete; Xs/Ws dead

    // zn: numpy-pairwise sum of squares per row (values == z row, from zs)
    if (t < 64) {
        float r8[8];
        #pragma unroll
        for (int s = 0; s < 8; s++) { float xx = zs[s * ZSTR + t]; r8[s] = xx * xx; }
        #pragma unroll
        for (int m = 1; m < 8; m++) {
            #pragma unroll
            for (int s = 0; s < 8; s++) { float xx = zs[(8 * m + s) * ZSTR + t]; r8[s] += xx * xx; }
        }
        zn_s[t] = ((r8[0] + r8[1]) + (r8[2] + r8[3])) + ((r8[4] + r8[5]) + (r8[6] + r8[7]));
    }

    // ---------------- dist phase (v0 loop verbatim; es aliases SH) ----------
    float* es = SH;                       // [64 k][ESTR]
    int rg = t & 15;                      // rows  4*rg + i
    int cg = t >> 4;                      // codes 8*cg + j (local)
    float bestd[4];
    int   bestj[4];
    #pragma unroll
    for (int i = 0; i < 4; i++) { bestd[i] = __builtin_huge_valf(); bestj[i] = 0; }

    for (int ch = 0; ch < 8; ch++) {
        int c0 = ch * 128;
        __syncthreads();   // protect es/en_s from prior readers (covers zn_s/conv at ch=0)
        {
            int k = t & 63, wv = t >> 6;
            #pragma unroll
            for (int m = 0; m < 8; m++) {
                int v = wv + 4 * m;       // 0..31
                float4 val;
                val.x = emb[(size_t)(c0 + 4 * v + 0) * ED + k];
                val.y = emb[(size_t)(c0 + 4 * v + 1) * ED + k];
                val.z = emb[(size_t)(c0 + 4 * v + 2) * ED + k];
                val.w = emb[(size_t)(c0 + 4 * v + 3) * ED + k];
                *(float4*)&es[k * ESTR + 4 * v] = val;
            }
            if (t < 32) {
                float4 ev4 = *(const float4*)&enorm[c0 + 4 * t];
                *(float4*)&en_s[4 * t] = ev4;
            }
        }
        __syncthreads();

        float acc[4][8];
        #pragma unroll
        for (int i = 0; i < 4; i++)
            #pragma unroll
            for (int j = 0; j < 8; j++) acc[i][j] = 0.0f;

        #pragma unroll 8
        for (int k = 0; k < 64; k++) {
            float4 xv = *(const float4*)&zs[k * ZSTR + 4 * rg];
            float4 e0 = *(const float4*)&es[k * ESTR + 8 * cg];
            float4 e1 = *(const float4*)&es[k * ESTR + 8 * cg + 4];
            float xa[4] = {xv.x, xv.y, xv.z, xv.w};
            float eb[8] = {e0.x, e0.y, e0.z, e0.w, e1.x, e1.y, e1.z, e1.w};
            #pragma unroll
            for (int i = 0; i < 4; i++)
                #pragma unroll
                for (int j = 0; j < 8; j++)
                    acc[i][j] = fmaf(xa[i], eb[j], acc[i][j]);
        }

        // epilogue: d = fl(fl(zn + en) - 2*dot); strict < keeps first index
        #pragma unroll
        for (int i = 0; i < 4; i++) {
            float zn = zn_s[4 * rg + i];
            #pragma unroll
            for (int j = 0; j < 8; j++) {
                int cl = 8 * cg + j;
                float A = zn + en_s[cl];
                float D = A - 2.0f * acc[i][j];
                if (D < bestd[i]) { bestd[i] = D; bestj[i] = c0 + cl; }
            }
        }
    }

    __syncthreads();   // es dead; overlay argmin scratch
    #pragma unroll
    for (int i = 0; i < 4; i++) {
        redd_s[cg * 64 + 4 * rg + i] = bestd[i];
        redj_s[cg * 64 + 4 * rg + i] = bestj[i];
    }
    __syncthreads();
    if (t < 64) {
        float bd = __builtin_huge_valf();
        int   bj = 0x7fffffff;
        #pragma unroll
        for (int c = 0; c < 16; c++) {
            float dd = redd_s[c * 64 + t];
            int   jj = redj_s[c * 64 + t];
            if (dd < bd || (dd == bd && jj < bj)) { bd = dd; bj = jj; }
        }
        int rowg = b * 1024 + t * 16 + p16;     // global zf row for local o=t
        bj_s[t]       = bj;
        out_idx[rowg] = (float)bj;              // min_idx as float
        atomicExch(&out_samp[bj], 1.0f);        // scattered, low contention
    }
    __syncthreads();

    // Fused STE epilogue: z from zs (bit-exact), emb gather, SSE partial.
    // thread t: local row r = t&63 (o), k-range [16*kq, 16*kq+16)
    {
        int r  = t & 63;
        int kq = t >> 6;
        int bj = bj_s[r];
        size_t n = (size_t)(b * 1024 + r * 16 + p16);
        const float* er = emb + (size_t)bj * ED + kq * 16;
        float sq = 0.0f;
        #pragma unroll
        for (int m = 0; m < 4; m++) {
            float4 ev = *(const float4*)&er[4 * m];
            int kk = kq * 16 + 4 * m;
            float zv0 = zs[(kk + 0) * ZSTR + r];
            float zv1 = zs[(kk + 1) * ZSTR + r];
            float zv2 = zs[(kk + 2) * ZSTR + r];
            float zv3 = zs[(kk + 3) * ZSTR + r];
            float d0 = ev.x - zv0, d1 = ev.y - zv1, d2 = ev.z - zv2, d3 = ev.w - zv3;
            float4 o4;
            o4.x = zv0 + d0; o4.y = zv1 + d1; o4.z = zv2 + d2; o4.w = zv3 + d3;
            *(float4*)&out_zq[n * ED + kk] = o4;
            sq += d0 * d0; sq += d1 * d1; sq += d2 * d2; sq += d3 * d3;
        }
        #pragma unroll
        for (int off = 32; off > 0; off >>= 1) sq += __shfl_down(sq, off, 64);
        if ((t & 63) == 0) warr[t >> 6] = sq;
    }
    __syncthreads();

    // Last-block loss reduction: release-fence + counter (512 blocks).
    if (t == 0) {
        ssep[bx] = (warr[0] + warr[1]) + (warr[2] + warr[3]);
        __threadfence();                       // make ssep visible device-wide
        unsigned int old = atomicAdd(counter, 1u);
        lastflag = (old == 511u) ? 1 : 0;
    }
    __syncthreads();
    if (lastflag) {
        __threadfence();                       // acquire: see all blocks' ssep
        const volatile float* sv = (const volatile float*)ssep;
        SD[t] = (double)sv[t] + (double)sv[t + 256];
        __syncthreads();
        #pragma unroll
        for (int off = 128; off > 0; off >>= 1) {
            if (t < off) SD[t] += SD[t + off];
            __syncthreads();
        }
        if (t < 64) {
            float v = 0.0f;
            #pragma unroll
            for (int m = 0; m < 16; m++) v += cpart[m * 64 + t];
            float sq = v * v;
            #pragma unroll
            for (int off = 32; off > 0; off >>= 1) sq += __shfl_down(sq, off, 64);
            if (t == 0) CS = sq / (1024.0f * 1024.0f);
        }
        __syncthreads();
        if (t == 0) {
            float m = (float)(SD[0] / (double)ZTOT);
            float loss = m + 0.25f * m;        // LEGACY: mse + BETA*mse
            out_loss[0] = loss + CS;
        }
    }
}

// ---------------------------------------------------------------------------
extern "C" void kernel_launch(void* const* d_in, const int* in_sizes, int n_in,
                              void* d_out, int out_size, void* d_ws, size_t ws_size,
                              hipStream_t stream) {
    (void)in_sizes; (void)n_in; (void)out_size; (void)ws_size;
    const float* z_     = (const float*)d_in[0];
    const float* conv_w = (const float*)d_in[1];
    const float* conv_b = (const float*)d_in[2];
    const float* emb    = (const float*)d_in[3];

    float* out      = (float*)d_out;
    float* out_zq   = out;
    float* out_loss = out + OFF_LOSS;
    float* out_samp = out + OFF_SAMP;
    float* out_idx  = out + OFF_IDX;

    float* ws    = (float*)d_ws;
    float* enorm = ws;                    // 1024 floats
    float* cpart = ws + 1024;             // 1024 floats
    float* ssep  = ws + 2048;             // 512 floats
    unsigned int* counter = (unsigned int*)(ws + 2560);

    k_con  <<<148, 256, 0, stream>>>(emb, out_samp, enorm, cpart, counter);
    k_fused<<<512, 256, 0, stream>>>(z_, conv_w, conv_b, emb, enorm, cpart,
                                     out_idx, out_samp, out_zq, ssep, out_loss, counter);
}

// Round 7
// 172.521 us; speedup vs baseline: 1.2674x; 1.2674x over previous
//
#include <hip/hip_runtime.h>

// Problem constants
#define BATCH   32
#define CIN     256
#define COUT    64
#define HW      1024          // 32*32
#define NE      1024          // codebook size
#define ED      64            // code dim
#define ZTOT    2097152       // BATCH*COUT*HW

// d_out layout (floats): z_q_st[ZTOT], loss[1], sampled[32768], min_idx[32768]
#define OFF_LOSS 2097152
#define OFF_SAMP 2097153
#define OFF_IDX  2129921

// LDS strides (floats). k-major, stride%32==4: measured conflict-free (R0/R1).
#define CXSTR 68    // conv Xs/Ws [64 c][64 + 4]
#define XSTR  68    // dist zs [64 k][64 row + 4]
#define ESTR  132   // dist es [64 k][128 code + 4]

// ---------------------------------------------------------------------------
// k_pre (R5 verbatim, proven ~26 us): conv blocks FIRST, then zero/norms.
// blocks 0..511   : conv, 64-px tile (R1-proven 4px x 4o per thread, 4 blk/CU)
// blocks 512..639 : zero out_samp (block 512 also zeroes the done-counter)
// blocks 640..655 : contrast partials (block-local inv-norms)
// blocks 656..659 : enorm
__global__ __launch_bounds__(256, 4) void k_pre(const float* __restrict__ x,
                                                const float* __restrict__ w,
                                                const float* __restrict__ bias,
                                                float* __restrict__ z,
                                                const float* __restrict__ emb,
                                                float* __restrict__ out_samp,
                                                float* __restrict__ enorm,
                                                float* __restrict__ cpart,
                                                unsigned int* __restrict__ counter) {
    __shared__ float SH[64 * CXSTR * 2];    // 34.8 KB, aliased per branch
    int bx = blockIdx.x;
    int t  = threadIdx.x;

    if (bx < 512) {                       // ---- conv (R1-proven tiling)
        float* Xs = SH;                   // [64 c][CXSTR]
        float* Ws = SH + 64 * CXSTR;      // [64 c][CXSTR]
        int b  = bx >> 4;                 // 0..31
        int p0 = (bx & 15) * 64;          // 0..960
        int pg = t & 15;                  // px: 4*pg + i
        int og = t >> 4;                  // o : 4*og + j
        float acc[4][4];
        #pragma unroll
        for (int i = 0; i < 4; i++)
            #pragma unroll
            for (int j = 0; j < 4; j++) acc[i][j] = 0.0f;

        for (int c0 = 0; c0 < CIN; c0 += 64) {
            __syncthreads();
            {
                int u = t & 15, cg2 = t >> 4;
                #pragma unroll
                for (int m = 0; m < 4; m++) {
                    int c = cg2 + 16 * m;
                    float4 v = *(const float4*)&x[(size_t)(b * CIN + c0 + c) * HW + p0 + 4 * u];
                    *(float4*)&Xs[c * CXSTR + 4 * u] = v;
                }
                #pragma unroll
                for (int m = 0; m < 4; m++) {
                    int o = cg2 + 16 * m;
                    float4 v = *(const float4*)&w[o * CIN + c0 + 4 * u];
                    Ws[(4 * u + 0) * CXSTR + o] = v.x;
                    Ws[(4 * u + 1) * CXSTR + o] = v.y;
                    Ws[(4 * u + 2) * CXSTR + o] = v.z;
                    Ws[(4 * u + 3) * CXSTR + o] = v.w;
                }
            }
            __syncthreads();
            #pragma unroll 8
            for (int k = 0; k < 64; k++) {
                float4 xv = *(const float4*)&Xs[k * CXSTR + 4 * pg];
                float4 wv = *(const float4*)&Ws[k * CXSTR + 4 * og];
                float xa[4] = {xv.x, xv.y, xv.z, xv.w};
                float wb[4] = {wv.x, wv.y, wv.z, wv.w};
                #pragma unroll
                for (int i = 0; i < 4; i++)
                    #pragma unroll
                    for (int j = 0; j < 4; j++)
                        acc[i][j] = fmaf(xa[i], wb[j], acc[i][j]);
            }
        }
        #pragma unroll
        for (int j = 0; j < 4; j++) {
            int o = 4 * og + j;
            float bv = bias[o];
            float4 out;
            out.x = acc[0][j] + bv;
            out.y = acc[1][j] + bv;
            out.z = acc[2][j] + bv;
            out.w = acc[3][j] + bv;
            *(float4*)&z[(size_t)(b * COUT + o) * HW + p0 + 4 * pg] = out;
        }
        return;
    }
    if (bx < 640) {                       // ---- zero sampled
        if (bx == 512 && t == 0) *counter = 0u;
        out_samp[(bx - 512) * 256 + t] = 0.0f;
        return;
    }
    if (bx < 656) {                       // ---- contrast partial (16 blocks)
        float* invl = SH;                 // [64]
        float* S    = SH + 64;            // [256]
        int b2 = bx - 640;
        int i0 = b2 * 64;
        if (t < 64) {
            const float* e = emb + (size_t)(i0 + t) * ED;
            float r8[8];
            #pragma unroll
            for (int s = 0; s < 8; s++) { float xx = e[s]; r8[s] = xx * xx; }
            #pragma unroll
            for (int m = 1; m < 8; m++) {
                #pragma unroll
                for (int s = 0; s < 8; s++) { float xx = e[8 * m + s]; r8[s] += xx * xx; }
            }
            float en = ((r8[0] + r8[1]) + (r8[2] + r8[3])) + ((r8[4] + r8[5]) + (r8[6] + r8[7]));
            invl[t] = 1.0f / sqrtf(en);
        }
        __syncthreads();
        int d = t & 63, q = t >> 6;
        float s = 0.0f;
        #pragma unroll
        for (int m = 0; m < 16; m++) {
            int il = q + 4 * m;
            s = fmaf(emb[(size_t)(i0 + il) * ED + d], invl[il], s);
        }
        S[t] = s;
        __syncthreads();
        if (t < 64)
            cpart[b2 * 64 + t] = (S[t] + S[t + 64]) + (S[t + 128] + S[t + 192]);
        return;
    }
    {                                     // ---- enorm (4 blocks: 656..659)
        int j = (bx - 656) * 256 + t;     // 0..1023
        const float* e = emb + (size_t)j * ED;
        float r8[8];
        #pragma unroll
        for (int s = 0; s < 8; s++) { float xx = e[s]; r8[s] = xx * xx; }
        #pragma unroll
        for (int m = 1; m < 8; m++) {
            #pragma unroll
            for (int s = 0; s < 8; s++) { float xx = e[8 * m + s]; r8[s] += xx * xx; }
        }
        enorm[j] = ((r8[0] + r8[1]) + (r8[2] + r8[3])) + ((r8[4] + r8[5]) + (r8[6] + r8[7]));
    }
}

// ---------------------------------------------------------------------------
// k_dist: v0's proven 71.6-us loop VERBATIM (4 rows x 8 codes per thread,
// 128-code full-K chunks, k-major conflict-free layout, 512 blocks = 8
// waves/CU). Only addition: last-block loss reduction (R5-proven fold) so
// k_final's launch is eliminated. All value chains bit-identical to R0/R1.
__global__ __launch_bounds__(256, 2) void k_dist(const float* __restrict__ z,
                                                 const float* __restrict__ emb,
                                                 const float* __restrict__ enorm,
                                                 const float* __restrict__ cpart,
                                                 float* __restrict__ out_idx,
                                                 float* __restrict__ out_samp,
                                                 float* __restrict__ out_zq,
                                                 float* __restrict__ ssep,
                                                 float* __restrict__ out_loss,
                                                 unsigned int* __restrict__ counter) {
    __shared__ float zs[64 * XSTR];      // [k][row] transposed
    __shared__ float es[64 * ESTR];      // [k][code_local]
    __shared__ float zn_s[64];
    __shared__ float en_s[128];
    __shared__ float redd_s[16 * 64];
    __shared__ int   redj_s[16 * 64];
    __shared__ int   bj_s[64];
    __shared__ float warr[4];
    __shared__ double SD[256];           // last-block loss tree (aligned)
    __shared__ int   lastflag;
    __shared__ float CS;
    int t = threadIdx.x;
    int row0 = blockIdx.x * 64;
    int rg = t & 15;     // rows  4*rg + i
    int cg = t >> 4;     // codes 8*cg + j (local)

    // stage zs transposed: zs[k][r]
    {
        int k = t & 63, wv = t >> 6;
        #pragma unroll
        for (int m = 0; m < 4; m++) {
            int v = wv + 4 * m;          // 0..15
            float4 val;
            val.x = z[(size_t)(row0 + 4 * v + 0) * ED + k];
            val.y = z[(size_t)(row0 + 4 * v + 1) * ED + k];
            val.z = z[(size_t)(row0 + 4 * v + 2) * ED + k];
            val.w = z[(size_t)(row0 + 4 * v + 3) * ED + k];
            *(float4*)&zs[k * XSTR + 4 * v] = val;
        }
    }
    // zn: numpy-pairwise sum of squares per row
    if (t < 64) {
        const float* zr = z + (size_t)(row0 + t) * ED;
        float r8[8];
        #pragma unroll
        for (int s = 0; s < 8; s++) { float xx = zr[s]; r8[s] = xx * xx; }
        #pragma unroll
        for (int m = 1; m < 8; m++) {
            #pragma unroll
            for (int s = 0; s < 8; s++) { float xx = zr[8 * m + s]; r8[s] += xx * xx; }
        }
        zn_s[t] = ((r8[0] + r8[1]) + (r8[2] + r8[3])) + ((r8[4] + r8[5]) + (r8[6] + r8[7]));
    }

    float bestd[4];
    int   bestj[4];
    #pragma unroll
    for (int i = 0; i < 4; i++) { bestd[i] = __builtin_huge_valf(); bestj[i] = 0; }

    for (int ch = 0; ch < 8; ch++) {
        int c0 = ch * 128;
        __syncthreads();   // protect es/en_s from prior-iteration readers
        {
            int k = t & 63, wv = t >> 6;
            #pragma unroll
            for (int m = 0; m < 8; m++) {
                int v = wv + 4 * m;      // 0..31
                float4 val;
                val.x = emb[(size_t)(c0 + 4 * v + 0) * ED + k];
                val.y = emb[(size_t)(c0 + 4 * v + 1) * ED + k];
                val.z = emb[(size_t)(c0 + 4 * v + 2) * ED + k];
                val.w = emb[(size_t)(c0 + 4 * v + 3) * ED + k];
                *(float4*)&es[k * ESTR + 4 * v] = val;
            }
            if (t < 32) {
                float4 ev4 = *(const float4*)&enorm[c0 + 4 * t];
                *(float4*)&en_s[4 * t] = ev4;
            }
        }
        __syncthreads();

        float acc[4][8];
        #pragma unroll
        for (int i = 0; i < 4; i++)
            #pragma unroll
            for (int j = 0; j < 8; j++) acc[i][j] = 0.0f;

        #pragma unroll 8
        for (int k = 0; k < 64; k++) {
            float4 xv = *(const float4*)&zs[k * XSTR + 4 * rg];
            float4 e0 = *(const float4*)&es[k * ESTR + 8 * cg];
            float4 e1 = *(const float4*)&es[k * ESTR + 8 * cg + 4];
            float xa[4] = {xv.x, xv.y, xv.z, xv.w};
            float eb[8] = {e0.x, e0.y, e0.z, e0.w, e1.x, e1.y, e1.z, e1.w};
            #pragma unroll
            for (int i = 0; i < 4; i++)
                #pragma unroll
                for (int j = 0; j < 8; j++)
                    acc[i][j] = fmaf(xa[i], eb[j], acc[i][j]);
        }

        // epilogue: d = fl(fl(zn + en) - 2*dot); strict < keeps first index
        #pragma unroll
        for (int i = 0; i < 4; i++) {
            float zn = zn_s[4 * rg + i];
            #pragma unroll
            for (int j = 0; j < 8; j++) {
                int cl = 8 * cg + j;
                float A = zn + en_s[cl];
                float D = A - 2.0f * acc[i][j];
                if (D < bestd[i]) { bestd[i] = D; bestj[i] = c0 + cl; }
            }
        }
    }

    #pragma unroll
    for (int i = 0; i < 4; i++) {
        redd_s[cg * 64 + 4 * rg + i] = bestd[i];
        redj_s[cg * 64 + 4 * rg + i] = bestj[i];
    }
    __syncthreads();
    if (t < 64) {
        float bd = __builtin_huge_valf();
        int   bj = 0x7fffffff;
        #pragma unroll
        for (int c = 0; c < 16; c++) {
            float dd = redd_s[c * 64 + t];
            int   jj = redj_s[c * 64 + t];
            if (dd < bd || (dd == bd && jj < bj)) { bd = dd; bj = jj; }
        }
        int rowg = row0 + t;
        bj_s[t]       = bj;
        out_idx[rowg] = (float)bj;              // min_idx as float
        atomicExch(&out_samp[bj], 1.0f);        // scattered, low contention
    }
    __syncthreads();

    // Fused STE epilogue: z from zs (bit-exact), emb gather, SSE partial.
    // thread t: row r = t&63, k-range [16*kq, 16*kq+16)
    {
        int r  = t & 63;
        int kq = t >> 6;
        int bj = bj_s[r];
        const float* er = emb + (size_t)bj * ED + kq * 16;
        float sq = 0.0f;
        #pragma unroll
        for (int m = 0; m < 4; m++) {
            float4 ev = *(const float4*)&er[4 * m];
            float zv0 = zs[(kq * 16 + 4 * m + 0) * XSTR + r];
            float zv1 = zs[(kq * 16 + 4 * m + 1) * XSTR + r];
            float zv2 = zs[(kq * 16 + 4 * m + 2) * XSTR + r];
            float zv3 = zs[(kq * 16 + 4 * m + 3) * XSTR + r];
            float d0 = ev.x - zv0, d1 = ev.y - zv1, d2 = ev.z - zv2, d3 = ev.w - zv3;
            float4 o4;
            o4.x = zv0 + d0; o4.y = zv1 + d1; o4.z = zv2 + d2; o4.w = zv3 + d3;
            *(float4*)&out_zq[(size_t)(row0 + r) * ED + kq * 16 + 4 * m] = o4;
            sq += d0 * d0; sq += d1 * d1; sq += d2 * d2; sq += d3 * d3;
        }
        #pragma unroll
        for (int off = 32; off > 0; off >>= 1) sq += __shfl_down(sq, off, 64);
        int lane = t & 63, wv = t >> 6;
        if (lane == 0) warr[wv] = sq;
    }
    __syncthreads();

    // Last-block loss reduction (R5-proven): release-fence + counter.
    if (t == 0) {
        ssep[blockIdx.x] = (warr[0] + warr[1]) + (warr[2] + warr[3]);
        __threadfence();                       // make ssep visible device-wide
        unsigned int old = atomicAdd(counter, 1u);
        lastflag = (old == 511u) ? 1 : 0;
    }
    __syncthreads();
    if (lastflag) {
        __threadfence();                       // acquire: see all blocks' ssep
        const volatile float* sv = (const volatile float*)ssep;
        SD[t] = (double)sv[t] + (double)sv[t + 256];
        __syncthreads();
        #pragma unroll
        for (int off = 128; off > 0; off >>= 1) {
            if (t < off) SD[t] += SD[t + off];
            __syncthreads();
        }
        if (t < 64) {
            float v = 0.0f;
            #pragma unroll
            for (int m = 0; m < 16; m++) v += cpart[m * 64 + t];
            float sq = v * v;
            #pragma unroll
            for (int off = 32; off > 0; off >>= 1) sq += __shfl_down(sq, off, 64);
            if (t == 0) CS = sq / (1024.0f * 1024.0f);
        }
        __syncthreads();
        if (t == 0) {
            float m = (float)(SD[0] / (double)ZTOT);
            float loss = m + 0.25f * m;        // LEGACY: mse + BETA*mse
            out_loss[0] = loss + CS;
        }
    }
}

// ---------------------------------------------------------------------------
extern "C" void kernel_launch(void* const* d_in, const int* in_sizes, int n_in,
                              void* d_out, int out_size, void* d_ws, size_t ws_size,
                              hipStream_t stream) {
    (void)in_sizes; (void)n_in; (void)out_size; (void)ws_size;
    const float* z_     = (const float*)d_in[0];
    const float* conv_w = (const float*)d_in[1];
    const float* conv_b = (const float*)d_in[2];
    const float* emb    = (const float*)d_in[3];

    float* out      = (float*)d_out;
    float* out_zq   = out;
    float* out_loss = out + OFF_LOSS;
    float* out_samp = out + OFF_SAMP;
    float* out_idx  = out + OFF_IDX;

    char*  ws       = (char*)d_ws;
    float* wz       = (float*)ws;                         // 2M floats (8 MB)
    float* enorm    = (float*)(ws + 8388608);             // 1024 floats
    float* cpart    = (float*)(ws + 8392704);             // 16*64 floats
    float* ssep     = (float*)(ws + 8396800);             // 512 floats
    unsigned int* counter = (unsigned int*)(ws + 8398848);

    k_pre  <<<660, 256, 0, stream>>>(z_, conv_w, conv_b, wz, emb, out_samp, enorm, cpart, counter);
    k_dist <<<512, 256, 0, stream>>>(wz, emb, enorm, cpart, out_idx, out_samp, out_zq, ssep, out_loss, counter);
}

// Round 8
// 158.396 us; speedup vs baseline: 1.3804x; 1.0892x over previous
//
#include <hip/hip_runtime.h>

// Problem constants
#define BATCH   32
#define CIN     256
#define COUT    64
#define HW      1024          // 32*32
#define NE      1024          // codebook size
#define ED      64            // code dim
#define ZTOT    2097152       // BATCH*COUT*HW

// d_out layout (floats): z_q_st[ZTOT], loss[1], sampled[32768], min_idx[32768]
#define OFF_LOSS 2097152
#define OFF_SAMP 2097153
#define OFF_IDX  2129921

// LDS strides (floats). k-major, stride%32==4: measured conflict-free (R0/R1).
#define CXSTR 68    // conv Xs/Ws [64 c][64 + 4]
#define XSTR  68    // dist zs [64 k][64 row + 4]
#define ESTR  132   // dist es [64 k][128 code + 4]

// ---------------------------------------------------------------------------
// k_pre (R5 verbatim, proven ~26 us): conv blocks FIRST, then zero/norms.
// blocks 0..511   : conv, 64-px tile (R1-proven 4px x 4o per thread)
// blocks 512..639 : zero out_samp
// blocks 640..655 : contrast partials (block-local inv-norms)
// blocks 656..659 : enorm
__global__ __launch_bounds__(256, 4) void k_pre(const float* __restrict__ x,
                                                const float* __restrict__ w,
                                                const float* __restrict__ bias,
                                                float* __restrict__ z,
                                                const float* __restrict__ emb,
                                                float* __restrict__ out_samp,
                                                float* __restrict__ enorm,
                                                float* __restrict__ cpart) {
    __shared__ float SH[64 * CXSTR * 2];    // 34.8 KB, aliased per branch
    int bx = blockIdx.x;
    int t  = threadIdx.x;

    if (bx < 512) {                       // ---- conv (R1-proven tiling)
        float* Xs = SH;                   // [64 c][CXSTR]
        float* Ws = SH + 64 * CXSTR;      // [64 c][CXSTR]
        int b  = bx >> 4;                 // 0..31
        int p0 = (bx & 15) * 64;          // 0..960
        int pg = t & 15;                  // px: 4*pg + i
        int og = t >> 4;                  // o : 4*og + j
        float acc[4][4];
        #pragma unroll
        for (int i = 0; i < 4; i++)
            #pragma unroll
            for (int j = 0; j < 4; j++) acc[i][j] = 0.0f;

        for (int c0 = 0; c0 < CIN; c0 += 64) {
            __syncthreads();
            {
                int u = t & 15, cg2 = t >> 4;
                #pragma unroll
                for (int m = 0; m < 4; m++) {
                    int c = cg2 + 16 * m;
                    float4 v = *(const float4*)&x[(size_t)(b * CIN + c0 + c) * HW + p0 + 4 * u];
                    *(float4*)&Xs[c * CXSTR + 4 * u] = v;
                }
                #pragma unroll
                for (int m = 0; m < 4; m++) {
                    int o = cg2 + 16 * m;
                    float4 v = *(const float4*)&w[o * CIN + c0 + 4 * u];
                    Ws[(4 * u + 0) * CXSTR + o] = v.x;
                    Ws[(4 * u + 1) * CXSTR + o] = v.y;
                    Ws[(4 * u + 2) * CXSTR + o] = v.z;
                    Ws[(4 * u + 3) * CXSTR + o] = v.w;
                }
            }
            __syncthreads();
            #pragma unroll 8
            for (int k = 0; k < 64; k++) {
                float4 xv = *(const float4*)&Xs[k * CXSTR + 4 * pg];
                float4 wv = *(const float4*)&Ws[k * CXSTR + 4 * og];
                float xa[4] = {xv.x, xv.y, xv.z, xv.w};
                float wb[4] = {wv.x, wv.y, wv.z, wv.w};
                #pragma unroll
                for (int i = 0; i < 4; i++)
                    #pragma unroll
                    for (int j = 0; j < 4; j++)
                        acc[i][j] = fmaf(xa[i], wb[j], acc[i][j]);
            }
        }
        #pragma unroll
        for (int j = 0; j < 4; j++) {
            int o = 4 * og + j;
            float bv = bias[o];
            float4 out;
            out.x = acc[0][j] + bv;
            out.y = acc[1][j] + bv;
            out.z = acc[2][j] + bv;
            out.w = acc[3][j] + bv;
            *(float4*)&z[(size_t)(b * COUT + o) * HW + p0 + 4 * pg] = out;
        }
        return;
    }
    if (bx < 640) {                       // ---- zero sampled
        out_samp[(bx - 512) * 256 + t] = 0.0f;
        return;
    }
    if (bx < 656) {                       // ---- contrast partial (16 blocks)
        float* invl = SH;                 // [64]
        float* S    = SH + 64;            // [256]
        int b2 = bx - 640;
        int i0 = b2 * 64;
        if (t < 64) {
            const float* e = emb + (size_t)(i0 + t) * ED;
            float r8[8];
            #pragma unroll
            for (int s = 0; s < 8; s++) { float xx = e[s]; r8[s] = xx * xx; }
            #pragma unroll
            for (int m = 1; m < 8; m++) {
                #pragma unroll
                for (int s = 0; s < 8; s++) { float xx = e[8 * m + s]; r8[s] += xx * xx; }
            }
            float en = ((r8[0] + r8[1]) + (r8[2] + r8[3])) + ((r8[4] + r8[5]) + (r8[6] + r8[7]));
            invl[t] = 1.0f / sqrtf(en);
        }
        __syncthreads();
        int d = t & 63, q = t >> 6;
        float s = 0.0f;
        #pragma unroll
        for (int m = 0; m < 16; m++) {
            int il = q + 4 * m;
            s = fmaf(emb[(size_t)(i0 + il) * ED + d], invl[il], s);
        }
        S[t] = s;
        __syncthreads();
        if (t < 64)
            cpart[b2 * 64 + t] = (S[t] + S[t + 64]) + (S[t + 128] + S[t + 192]);
        return;
    }
    {                                     // ---- enorm (4 blocks: 656..659)
        int j = (bx - 656) * 256 + t;     // 0..1023
        const float* e = emb + (size_t)j * ED;
        float r8[8];
        #pragma unroll
        for (int s = 0; s < 8; s++) { float xx = e[s]; r8[s] = xx * xx; }
        #pragma unroll
        for (int m = 1; m < 8; m++) {
            #pragma unroll
            for (int s = 0; s < 8; s++) { float xx = e[8 * m + s]; r8[s] += xx * xx; }
        }
        enorm[j] = ((r8[0] + r8[1]) + (r8[2] + r8[3])) + ((r8[4] + r8[5]) + (r8[6] + r8[7]));
    }
}

// ---------------------------------------------------------------------------
// k_dist: R0's proven 71.6-us kernel BYTE-FOR-BYTE (4 rows x 8 codes per
// thread, 128-code full-K chunks, k-major conflict-free layout, 512 blocks).
// NO threadfence/fold: R7 showed the device-scope release fence every block
// executed cost ~18 us in write-drain stalls (90.0 vs 71.6 us, VALUBusy
// 41% vs 52%). Loss reduction is a separate 1-block launch again.
__global__ __launch_bounds__(256, 2) void k_dist(const float* __restrict__ z,
                                                 const float* __restrict__ emb,
                                                 const float* __restrict__ enorm,
                                                 float* __restrict__ out_idx,
                                                 float* __restrict__ out_samp,
                                                 float* __restrict__ out_zq,
                                                 float* __restrict__ ssep) {
    __shared__ float zs[64 * XSTR];      // [k][row] transposed
    __shared__ float es[64 * ESTR];      // [k][code_local]
    __shared__ float zn_s[64];
    __shared__ float en_s[128];
    __shared__ float redd_s[16 * 64];
    __shared__ int   redj_s[16 * 64];
    __shared__ int   bj_s[64];
    __shared__ float warr[4];
    int t = threadIdx.x;
    int row0 = blockIdx.x * 64;
    int rg = t & 15;     // rows  4*rg + i
    int cg = t >> 4;     // codes 8*cg + j (local)

    // stage zs transposed: zs[k][r]
    {
        int k = t & 63, wv = t >> 6;
        #pragma unroll
        for (int m = 0; m < 4; m++) {
            int v = wv + 4 * m;          // 0..15
            float4 val;
            val.x = z[(size_t)(row0 + 4 * v + 0) * ED + k];
            val.y = z[(size_t)(row0 + 4 * v + 1) * ED + k];
            val.z = z[(size_t)(row0 + 4 * v + 2) * ED + k];
            val.w = z[(size_t)(row0 + 4 * v + 3) * ED + k];
            *(float4*)&zs[k * XSTR + 4 * v] = val;
        }
    }
    // zn: numpy-pairwise sum of squares per row
    if (t < 64) {
        const float* zr = z + (size_t)(row0 + t) * ED;
        float r8[8];
        #pragma unroll
        for (int s = 0; s < 8; s++) { float xx = zr[s]; r8[s] = xx * xx; }
        #pragma unroll
        for (int m = 1; m < 8; m++) {
            #pragma unroll
            for (int s = 0; s < 8; s++) { float xx = zr[8 * m + s]; r8[s] += xx * xx; }
        }
        zn_s[t] = ((r8[0] + r8[1]) + (r8[2] + r8[3])) + ((r8[4] + r8[5]) + (r8[6] + r8[7]));
    }

    float bestd[4];
    int   bestj[4];
    #pragma unroll
    for (int i = 0; i < 4; i++) { bestd[i] = __builtin_huge_valf(); bestj[i] = 0; }

    for (int ch = 0; ch < 8; ch++) {
        int c0 = ch * 128;
        __syncthreads();   // protect es/en_s from prior-iteration readers
        {
            int k = t & 63, wv = t >> 6;
            #pragma unroll
            for (int m = 0; m < 8; m++) {
                int v = wv + 4 * m;      // 0..31
                float4 val;
                val.x = emb[(size_t)(c0 + 4 * v + 0) * ED + k];
                val.y = emb[(size_t)(c0 + 4 * v + 1) * ED + k];
                val.z = emb[(size_t)(c0 + 4 * v + 2) * ED + k];
                val.w = emb[(size_t)(c0 + 4 * v + 3) * ED + k];
                *(float4*)&es[k * ESTR + 4 * v] = val;
            }
            if (t < 32) {
                float4 ev4 = *(const float4*)&enorm[c0 + 4 * t];
                *(float4*)&en_s[4 * t] = ev4;
            }
        }
        __syncthreads();

        float acc[4][8];
        #pragma unroll
        for (int i = 0; i < 4; i++)
            #pragma unroll
            for (int j = 0; j < 8; j++) acc[i][j] = 0.0f;

        #pragma unroll 8
        for (int k = 0; k < 64; k++) {
            float4 xv = *(const float4*)&zs[k * XSTR + 4 * rg];
            float4 e0 = *(const float4*)&es[k * ESTR + 8 * cg];
            float4 e1 = *(const float4*)&es[k * ESTR + 8 * cg + 4];
            float xa[4] = {xv.x, xv.y, xv.z, xv.w};
            float eb[8] = {e0.x, e0.y, e0.z, e0.w, e1.x, e1.y, e1.z, e1.w};
            #pragma unroll
            for (int i = 0; i < 4; i++)
                #pragma unroll
                for (int j = 0; j < 8; j++)
                    acc[i][j] = fmaf(xa[i], eb[j], acc[i][j]);
        }

        // epilogue: d = fl(fl(zn + en) - 2*dot); strict < keeps first index
        #pragma unroll
        for (int i = 0; i < 4; i++) {
            float zn = zn_s[4 * rg + i];
            #pragma unroll
            for (int j = 0; j < 8; j++) {
                int cl = 8 * cg + j;
                float A = zn + en_s[cl];
                float D = A - 2.0f * acc[i][j];
                if (D < bestd[i]) { bestd[i] = D; bestj[i] = c0 + cl; }
            }
        }
    }

    #pragma unroll
    for (int i = 0; i < 4; i++) {
        redd_s[cg * 64 + 4 * rg + i] = bestd[i];
        redj_s[cg * 64 + 4 * rg + i] = bestj[i];
    }
    __syncthreads();
    if (t < 64) {
        float bd = __builtin_huge_valf();
        int   bj = 0x7fffffff;
        #pragma unroll
        for (int c = 0; c < 16; c++) {
            float dd = redd_s[c * 64 + t];
            int   jj = redj_s[c * 64 + t];
            if (dd < bd || (dd == bd && jj < bj)) { bd = dd; bj = jj; }
        }
        int rowg = row0 + t;
        bj_s[t]       = bj;
        out_idx[rowg] = (float)bj;              // min_idx as float
        atomicExch(&out_samp[bj], 1.0f);        // scattered, low contention
    }
    __syncthreads();

    // Fused STE epilogue: z from zs (bit-exact), emb gather, SSE partial.
    // thread t: row r = t&63, k-range [16*kq, 16*kq+16)
    {
        int r  = t & 63;
        int kq = t >> 6;
        int bj = bj_s[r];
        const float* er = emb + (size_t)bj * ED + kq * 16;
        float sq = 0.0f;
        #pragma unroll
        for (int m = 0; m < 4; m++) {
            float4 ev = *(const float4*)&er[4 * m];
            float zv0 = zs[(kq * 16 + 4 * m + 0) * XSTR + r];
            float zv1 = zs[(kq * 16 + 4 * m + 1) * XSTR + r];
            float zv2 = zs[(kq * 16 + 4 * m + 2) * XSTR + r];
            float zv3 = zs[(kq * 16 + 4 * m + 3) * XSTR + r];
            float d0 = ev.x - zv0, d1 = ev.y - zv1, d2 = ev.z - zv2, d3 = ev.w - zv3;
            float4 o4;
            o4.x = zv0 + d0; o4.y = zv1 + d1; o4.z = zv2 + d2; o4.w = zv3 + d3;
            *(float4*)&out_zq[(size_t)(row0 + r) * ED + kq * 16 + 4 * m] = o4;
            sq += d0 * d0; sq += d1 * d1; sq += d2 * d2; sq += d3 * d3;
        }
        #pragma unroll
        for (int off = 32; off > 0; off >>= 1) sq += __shfl_down(sq, off, 64);
        int lane = t & 63, wv = t >> 6;
        if (lane == 0) warr[wv] = sq;
    }
    __syncthreads();
    if (t == 0)
        ssep[blockIdx.x] = (warr[0] + warr[1]) + (warr[2] + warr[3]);
}

// ---------------------------------------------------------------------------
// k_final (R0 verbatim): deterministic combine of 512 SSE partials (double
// tree) and the 16x64 contrastive partials; writes the loss scalar.
__global__ __launch_bounds__(256) void k_final(const float* __restrict__ ssep,
                                               const float* __restrict__ cpart,
                                               float* __restrict__ out_loss) {
    __shared__ double SD[256];
    __shared__ float  CS;
    int t = threadIdx.x;
    SD[t] = (double)ssep[t] + (double)ssep[t + 256];
    __syncthreads();
    #pragma unroll
    for (int off = 128; off > 0; off >>= 1) {
        if (t < off) SD[t] += SD[t + off];
        __syncthreads();
    }
    if (t < 64) {
        float v = 0.0f;
        #pragma unroll
        for (int m = 0; m < 16; m++) v += cpart[m * 64 + t];
        float sq = v * v;
        #pragma unroll
        for (int off = 32; off > 0; off >>= 1) sq += __shfl_down(sq, off, 64);
        if (t == 0) CS = sq / (1024.0f * 1024.0f);
    }
    __syncthreads();
    if (t == 0) {
        float m = (float)(SD[0] / (double)ZTOT);
        float loss = m + 0.25f * m;         // LEGACY: mse + BETA*mse
        out_loss[0] = loss + CS;
    }
}

// ---------------------------------------------------------------------------
extern "C" void kernel_launch(void* const* d_in, const int* in_sizes, int n_in,
                              void* d_out, int out_size, void* d_ws, size_t ws_size,
                              hipStream_t stream) {
    (void)in_sizes; (void)n_in; (void)out_size; (void)ws_size;
    const float* z_     = (const float*)d_in[0];
    const float* conv_w = (const float*)d_in[1];
    const float* conv_b = (const float*)d_in[2];
    const float* emb    = (const float*)d_in[3];

    float* out      = (float*)d_out;
    float* out_zq   = out;
    float* out_loss = out + OFF_LOSS;
    float* out_samp = out + OFF_SAMP;
    float* out_idx  = out + OFF_IDX;

    char*  ws       = (char*)d_ws;
    float* wz       = (float*)ws;                         // 2M floats (8 MB)
    float* enorm    = (float*)(ws + 8388608);             // 1024 floats
    float* cpart    = (float*)(ws + 8392704);             // 16*64 floats
    float* ssep     = (float*)(ws + 8396800);             // 512 floats

    k_pre  <<<660, 256, 0, stream>>>(z_, conv_w, conv_b, wz, emb, out_samp, enorm, cpart);
    k_dist <<<512, 256, 0, stream>>>(wz, emb, enorm, out_idx, out_samp, out_zq, ssep);
    k_final<<<1,   256, 0, stream>>>(ssep, cpart, out_loss);
}